// Round 4
// baseline (91.318 us; speedup 1.0000x reference)
//
#include <hip/hip_runtime.h>

#define B_ 2
#define N_ 512
#define C_ 128   // HIDDEN_DIM
#define A_ 64    // ATTN_DIM
#define H_ 128

#define SC2L 2.885390081777927f     // 2*log2(e): exp(2x) = 2^(SC2L*x)
#define NEG2LE -2.885390081777927f  // -2*log2(e)

// workspace layout (float offsets)
#define OFF_V   0                           // v = exp(2 h_o) fp32 [g][a]
#define OFF_UT8 (OFF_V   + B_*N_*A_)        // u bf16 [b][a/8][n][8]
#define OFF_US8 (OFF_UT8 + B_*N_*A_/2)      // u bf16 [b][j/8][a][8]
#define OFF_XYP (OFF_US8 + B_*N_*A_/2)      // Xy bf16 pairs [b][j/2][h]

#define WES_STRIDE 130                       // padded We^T leading dim

__device__ __forceinline__ float fexp2(float x) { return __builtin_amdgcn_exp2f(x); }
__device__ __forceinline__ float frcp(float x)  { return __builtin_amdgcn_rcpf(x); }
__device__ __forceinline__ unsigned f2bf(float x) {   // fp32 -> bf16 bits (RNE)
  unsigned u = __float_as_uint(x);
  return (u + 0x7fffu + ((u >> 16) & 1u)) >> 16;
}
__device__ __forceinline__ float bf_lo(unsigned d) { return __uint_as_float(d << 16); }
__device__ __forceinline__ float bf_hi(unsigned d) { return __uint_as_float(d & 0xffff0000u); }

// ---------------- kernel 1: projections -> v (fp32), u & Xy (bf16) --------
// 128 blocks x 1024 threads, 8 rows/block. rp = t&3 selects the row pair;
// groups of 4 adjacent lanes read the SAME weight address -> wave coalescer
// merges them. Aggregate weight traffic 32 MB (round 3) -> 16 MB.
// Per-row FMA order identical -> bit-identical outputs.
__global__ __launch_bounds__(1024) void proj_kernel(
    const float* __restrict__ X, const float* __restrict__ by,
    const float* __restrict__ Wo, const float* __restrict__ W1,
    const float* __restrict__ Wy, float* __restrict__ ws) {
  __shared__ float xs[8*C_];
  int row0 = blockIdx.x * 8;            // global row base; 8 | N so no batch straddle
  int t = threadIdx.x;
  xs[t] = X[(size_t)row0*C_ + t];       // 1024 threads stage 8 rows
  __syncthreads();

  int rp = t & 3;                       // row-pair: rows rp*2, rp*2+1 (block-local)
  int cu = t >> 2;                      // 0..255 column unit
  const float* wrow;
  int col;
  if (cu < 64)       { col = cu;        wrow = Wo + (size_t)col*C_; }
  else if (cu < 128) { col = cu - 64;   wrow = W1 + (size_t)col*C_; }
  else               { col = cu - 128;  wrow = Wy + (size_t)col*C_; }

  const float* x0 = xs + (rp*2)*C_;
  const float* x1 = xs + (rp*2 + 1)*C_;
  const float4* w4 = (const float4*)wrow;
  float acc0 = 0.f, acc1 = 0.f;
  #pragma unroll 8
  for (int c4 = 0; c4 < C_/4; ++c4) {
    float4 w = w4[c4];
    int c = c4*4;
    acc0 = fmaf(x0[c+0], w.x, acc0);  acc1 = fmaf(x1[c+0], w.x, acc1);
    acc0 = fmaf(x0[c+1], w.y, acc0);  acc1 = fmaf(x1[c+1], w.y, acc1);
    acc0 = fmaf(x0[c+2], w.z, acc0);  acc1 = fmaf(x1[c+2], w.z, acc1);
    acc0 = fmaf(x0[c+3], w.w, acc0);  acc1 = fmaf(x1[c+3], w.w, acc1);
  }

  int grow = row0 + rp*2;               // global row of acc0 (even)
  int b = grow >> 9, n0 = grow & (N_-1);

  if (cu < 64) {                        // v = exp(2 h_o), fp32
    float* o = ws + OFF_V + (size_t)grow*A_ + col;
    o[0] = fexp2(SC2L * acc0);
    o[A_] = fexp2(SC2L * acc1);
  } else if (cu < 128) {                // u = exp(2 h_1), bf16, two layouts
    int a = col;
    unsigned u0 = f2bf(fexp2(SC2L * acc0));
    unsigned u1 = f2bf(fexp2(SC2L * acc1));
    unsigned short* ut = (unsigned short*)(ws + OFF_UT8);
    size_t bA = ((size_t)(b*8 + (a >> 3))*N_ + n0)*8 + (a & 7);
    ut[bA] = (unsigned short)u0;
    ut[bA + 8] = (unsigned short)u1;
    unsigned short* us = (unsigned short*)(ws + OFF_US8);
    size_t bC = ((size_t)(b*64 + (n0 >> 3))*A_ + a)*8 + (n0 & 7);
    us[bC] = (unsigned short)u0;
    us[bC + 1] = (unsigned short)u1;
  } else {                              // Xy bf16 pairs [b][k][h]
    int h = col;
    float bb = by[h];
    unsigned xv0 = f2bf(acc0 + bb);
    unsigned xv1 = f2bf(acc1 + bb);
    unsigned* xp = (unsigned*)(ws + OFF_XYP);
    xp[(size_t)(b*(N_/2) + (n0 >> 1))*H_ + h] = xv0 | (xv1 << 16);
  }
}

// ---------------- kernel 2: attention, TI=4, 1024 threads ----------------
// 256 blocks x 1024 threads = 1 block/CU (16 waves/CU). Unchanged from
// round 2 (pipe-balanced: VALU ~2080 cy/wave vs trans ~2048 cy/wave).
__global__ __launch_bounds__(1024) void attn_kernel(
    const float* __restrict__ Wphi, const float* __restrict__ be,
    const float* __restrict__ We,
    const float* __restrict__ ws, float* __restrict__ out) {
  __shared__ __align__(16) float pkv[4][A_]; // v rows (1 KB)
  __shared__ __align__(16) float pkw[A_];    // wphi
  __shared__ float sc[4][N_];                // p_j per row (8 KB)
  __shared__ float reds[4][8];               // per-wave denom partials
  __shared__ float ebw[4][16][A_];           // ebar partials (16 KB)
  __shared__ float ebar[4][A_];
  __shared__ __align__(16) float p1s[4][32][H_];  // part1 partials (64 KB)
  __shared__ float wes[A_*WES_STRIDE];       // We^T [a][h] padded (32.5 KB)

  int t = threadIdx.x;
  int w = t >> 6, lane = t & 63;
  int blk = blockIdx.x;                      // 0..255
  int b = blk >> 7;
  int i0 = (blk & 127) * 4;
  int g0 = b*N_ + i0;

  const uint4* ut8 = (const uint4*)((const unsigned short*)(ws + OFF_UT8))
                     + (size_t)b*8*N_;
  const uint4* us8 = (const uint4*)((const unsigned short*)(ws + OFF_US8))
                     + (size_t)b*64*A_;
  const uint4* xy4 = (const uint4*)((const unsigned*)(ws + OFF_XYP))
                     + (size_t)b*(N_/2)*(H_/4);

  if (t < 4*A_) {
    int r = t >> 6, a = t & 63;
    pkv[r][a] = ws[OFF_V + (size_t)(g0 + r)*A_ + a];
  } else if (t < 5*A_) {
    pkw[t - 4*A_] = Wphi[t - 4*A_];
  }
  // stage We^T: coalesced global read, 2-way-aliased (free) LDS write
  #pragma unroll
  for (int e = t; e < H_*A_; e += 1024) {
    int h = e >> 6, a = e & 63;
    wes[a*WES_STRIDE + h] = We[e];
  }
  __syncthreads();

  // ---- Pass A: thread = (r2 = t>>9, j = t&511); covers rows r2 and r2+2.
  {
    int r2 = t >> 9, j = t & 511;
    const float4* pvA = (const float4*)pkv[r2];
    const float4* pvB = (const float4*)pkv[r2 + 2];
    const float4* pw4 = (const float4*)pkw;
    float sA = 0.f, sB = 0.f;
    #pragma unroll
    for (int g = 0; g < 8; ++g) {
      uint4 d = ut8[(size_t)g*N_ + j];
      float4 a0 = pvA[2*g], a1 = pvA[2*g + 1];
      float4 b0 = pvB[2*g], b1 = pvB[2*g + 1];
      float4 w0 = pw4[2*g], w1 = pw4[2*g + 1];
      float u0 = bf_lo(d.x), u1 = bf_hi(d.x), u2 = bf_lo(d.y), u3 = bf_hi(d.y);
      float u4 = bf_lo(d.z), u5 = bf_hi(d.z), u6 = bf_lo(d.w), u7 = bf_hi(d.w);
      sA = fmaf(w0.x, frcp(fmaf(a0.x, u0, 1.f)), sA);
      sB = fmaf(w0.x, frcp(fmaf(b0.x, u0, 1.f)), sB);
      sA = fmaf(w0.y, frcp(fmaf(a0.y, u1, 1.f)), sA);
      sB = fmaf(w0.y, frcp(fmaf(b0.y, u1, 1.f)), sB);
      sA = fmaf(w0.z, frcp(fmaf(a0.z, u2, 1.f)), sA);
      sB = fmaf(w0.z, frcp(fmaf(b0.z, u2, 1.f)), sB);
      sA = fmaf(w0.w, frcp(fmaf(a0.w, u3, 1.f)), sA);
      sB = fmaf(w0.w, frcp(fmaf(b0.w, u3, 1.f)), sB);
      sA = fmaf(w1.x, frcp(fmaf(a1.x, u4, 1.f)), sA);
      sB = fmaf(w1.x, frcp(fmaf(b1.x, u4, 1.f)), sB);
      sA = fmaf(w1.y, frcp(fmaf(a1.y, u5, 1.f)), sA);
      sB = fmaf(w1.y, frcp(fmaf(b1.y, u5, 1.f)), sB);
      sA = fmaf(w1.z, frcp(fmaf(a1.z, u6, 1.f)), sA);
      sB = fmaf(w1.z, frcp(fmaf(b1.z, u6, 1.f)), sB);
      sA = fmaf(w1.w, frcp(fmaf(a1.w, u7, 1.f)), sA);
      sB = fmaf(w1.w, frcp(fmaf(b1.w, u7, 1.f)), sB);
    }
    float pA = fexp2(NEG2LE * sA);           // shift-free softmax numerators
    float pB = fexp2(NEG2LE * sB);
    sc[r2][j] = pA;
    sc[r2 + 2][j] = pB;
    float qA = pA, qB = pB;
    #pragma unroll
    for (int m = 1; m < 64; m <<= 1) {
      qA += __shfl_xor(qA, m);
      qB += __shfl_xor(qB, m);
    }
    if (lane == 0) {                         // w>>3 == r2
      reds[r2][w & 7] = qA;
      reds[r2 + 2][w & 7] = qB;
    }
  }
  __syncthreads();

  // ---- Pass C: lane = a; wave w covers octets o = oo*16 + w, ALL 4 rows
  {
    float v0 = pkv[0][lane], v1 = pkv[1][lane];
    float v2 = pkv[2][lane], v3 = pkv[3][lane];
    const float4* s40 = (const float4*)sc[0];
    const float4* s41 = (const float4*)sc[1];
    const float4* s42 = (const float4*)sc[2];
    const float4* s43 = (const float4*)sc[3];
    float c0 = 0.f, c1 = 0.f, c2 = 0.f, c3 = 0.f;
    #pragma unroll
    for (int oo = 0; oo < 4; ++oo) {
      int o = oo*16 + w;
      uint4 d = us8[(size_t)o*A_ + lane];
      float u0 = bf_lo(d.x), u1 = bf_hi(d.x), u2 = bf_lo(d.y), u3 = bf_hi(d.y);
      float u4 = bf_lo(d.z), u5 = bf_hi(d.z), u6 = bf_lo(d.w), u7 = bf_hi(d.w);
      float4 pA0 = s40[o*2], pB0 = s40[o*2 + 1];
      float4 pA1 = s41[o*2], pB1 = s41[o*2 + 1];
      float4 pA2 = s42[o*2], pB2 = s42[o*2 + 1];
      float4 pA3 = s43[o*2], pB3 = s43[o*2 + 1];
      #define PC_STEP(UU, F) { \
        float r0 = frcp(fmaf(v0, UU, 1.f)); \
        float r1 = frcp(fmaf(v1, UU, 1.f)); \
        float r2v = frcp(fmaf(v2, UU, 1.f)); \
        float r3v = frcp(fmaf(v3, UU, 1.f)); \
        c0 = fmaf(pA0.F, r0, c0); c1 = fmaf(pA1.F, r1, c1); \
        c2 = fmaf(pA2.F, r2v, c2); c3 = fmaf(pA3.F, r3v, c3); }
      #define PC_STEP2(UU, F) { \
        float r0 = frcp(fmaf(v0, UU, 1.f)); \
        float r1 = frcp(fmaf(v1, UU, 1.f)); \
        float r2v = frcp(fmaf(v2, UU, 1.f)); \
        float r3v = frcp(fmaf(v3, UU, 1.f)); \
        c0 = fmaf(pB0.F, r0, c0); c1 = fmaf(pB1.F, r1, c1); \
        c2 = fmaf(pB2.F, r2v, c2); c3 = fmaf(pB3.F, r3v, c3); }
      PC_STEP(u0, x) PC_STEP(u1, y) PC_STEP(u2, z) PC_STEP(u3, w)
      PC_STEP2(u4, x) PC_STEP2(u5, y) PC_STEP2(u6, z) PC_STEP2(u7, w)
      #undef PC_STEP
      #undef PC_STEP2
    }
    ebw[0][w][lane] = c0;
    ebw[1][w][lane] = c1;
    ebw[2][w][lane] = c2;
    ebw[3][w][lane] = c3;
  }

  // ---- part1: thread = (qd = t>>5 in [0,32), h4 = t&31); each Xy-load
  // feeds all 4 P-rows.
  {
    int h4 = t & 31, qd = t >> 5;
    float s00=0.f,s01=0.f,s02=0.f,s03=0.f;
    float s10=0.f,s11=0.f,s12=0.f,s13=0.f;
    float s20=0.f,s21=0.f,s22=0.f,s23=0.f;
    float s30=0.f,s31=0.f,s32=0.f,s33=0.f;
    const float2* p20 = (const float2*)sc[0];
    const float2* p21 = (const float2*)sc[1];
    const float2* p22 = (const float2*)sc[2];
    const float2* p23 = (const float2*)sc[3];
    #pragma unroll
    for (int kc = 0; kc < 8; ++kc) {
      int k = qd*8 + kc;
      uint4 d = xy4[(size_t)k*(H_/4) + h4];
      float2 P0 = p20[k], P1 = p21[k], P2 = p22[k], P3 = p23[k];
      float xa = bf_lo(d.x), xb = bf_hi(d.x);
      float xc = bf_lo(d.y), xd = bf_hi(d.y);
      float xe = bf_lo(d.z), xf = bf_hi(d.z);
      float xg = bf_lo(d.w), xh = bf_hi(d.w);
      s00 = fmaf(P0.x, xa, s00); s00 = fmaf(P0.y, xb, s00);
      s01 = fmaf(P0.x, xc, s01); s01 = fmaf(P0.y, xd, s01);
      s02 = fmaf(P0.x, xe, s02); s02 = fmaf(P0.y, xf, s02);
      s03 = fmaf(P0.x, xg, s03); s03 = fmaf(P0.y, xh, s03);
      s10 = fmaf(P1.x, xa, s10); s10 = fmaf(P1.y, xb, s10);
      s11 = fmaf(P1.x, xc, s11); s11 = fmaf(P1.y, xd, s11);
      s12 = fmaf(P1.x, xe, s12); s12 = fmaf(P1.y, xf, s12);
      s13 = fmaf(P1.x, xg, s13); s13 = fmaf(P1.y, xh, s13);
      s20 = fmaf(P2.x, xa, s20); s20 = fmaf(P2.y, xb, s20);
      s21 = fmaf(P2.x, xc, s21); s21 = fmaf(P2.y, xd, s21);
      s22 = fmaf(P2.x, xe, s22); s22 = fmaf(P2.y, xf, s22);
      s23 = fmaf(P2.x, xg, s23); s23 = fmaf(P2.y, xh, s23);
      s30 = fmaf(P3.x, xa, s30); s30 = fmaf(P3.y, xb, s30);
      s31 = fmaf(P3.x, xc, s31); s31 = fmaf(P3.y, xd, s31);
      s32 = fmaf(P3.x, xe, s32); s32 = fmaf(P3.y, xf, s32);
      s33 = fmaf(P3.x, xg, s33); s33 = fmaf(P3.y, xh, s33);
    }
    *(float4*)&p1s[0][qd][h4*4] = make_float4(s00, s01, s02, s03);
    *(float4*)&p1s[1][qd][h4*4] = make_float4(s10, s11, s12, s13);
    *(float4*)&p1s[2][qd][h4*4] = make_float4(s20, s21, s22, s23);
    *(float4*)&p1s[3][qd][h4*4] = make_float4(s30, s31, s32, s33);
  }
  __syncthreads();

  // ---- reduce ebar: ebar_un[r][a] = l_r - 2*sum_w ebw[r][w][a]
  if (t < 4*A_) {
    int r = t >> 6, a = t & 63;
    float e = 0.f;
    #pragma unroll
    for (int k = 0; k < 16; ++k) e += ebw[r][k][a];
    float l = 0.f;
    #pragma unroll
    for (int k = 0; k < 8; ++k) l += reds[r][k];
    ebar[r][a] = l - 2.0f*e;
  }
  __syncthreads();

  // ---- epilogue: out = (part1_un + We^T·ebar_un)/l + be
  if (t < 4*H_) {
    int r = t >> 7, h = t & 127;
    float l = 0.f;
    #pragma unroll
    for (int k = 0; k < 8; ++k) l += reds[r][k];
    float acc = 0.f;
    #pragma unroll
    for (int k = 0; k < 32; ++k) acc += p1s[r][k][h];
    float e2 = 0.f;
    #pragma unroll 8
    for (int a = 0; a < A_; ++a) e2 = fmaf(ebar[r][a], wes[a*WES_STRIDE + h], e2);
    out[(size_t)(g0 + r)*H_ + h] = (acc + e2) * frcp(l) + be[h];
  }
}

extern "C" void kernel_launch(void* const* d_in, const int* in_sizes, int n_in,
                              void* d_out, int out_size, void* d_ws, size_t ws_size,
                              hipStream_t stream) {
  const float* X    = (const float*)d_in[0];
  const float* Wo   = (const float*)d_in[1];
  const float* W1   = (const float*)d_in[2];
  const float* Wphi = (const float*)d_in[3];
  const float* Wy   = (const float*)d_in[4];
  const float* by   = (const float*)d_in[5];
  const float* We   = (const float*)d_in[6];
  const float* be   = (const float*)d_in[7];
  float* out = (float*)d_out;
  float* ws  = (float*)d_ws;

  hipLaunchKernelGGL(proj_kernel, dim3(B_*N_/8), dim3(1024), 0, stream,
                     X, by, Wo, W1, Wy, ws);
  hipLaunchKernelGGL(attn_kernel, dim3(B_*N_/4), dim3(1024), 0, stream,
                     Wphi, be, We, ws, out);
}

// Round 6
// 86.769 us; speedup vs baseline: 1.0524x; 1.0524x over previous
//
#include <hip/hip_runtime.h>

#define B_ 2
#define N_ 512
#define C_ 128   // HIDDEN_DIM
#define A_ 64    // ATTN_DIM
#define H_ 128

#define SC2L 2.885390081777927f     // 2*log2(e): exp(2x) = 2^(SC2L*x)
#define NEG2LE -2.885390081777927f  // -2*log2(e)

// workspace layout (float offsets)
#define OFF_V   0                           // v = exp(2 h_o) fp32 [g][a]
#define OFF_UT8 (OFF_V   + B_*N_*A_)        // u bf16 [b][a/8][n][8]
#define OFF_US8 (OFF_UT8 + B_*N_*A_/2)      // u bf16 [b][j/8][a][8]
#define OFF_XYP (OFF_US8 + B_*N_*A_/2)      // Xy bf16 pairs [b][j/2][h]

#define WES_STRIDE 130                       // padded We^T leading dim

__device__ __forceinline__ float fexp2(float x) { return __builtin_amdgcn_exp2f(x); }
__device__ __forceinline__ float frcp(float x)  { return __builtin_amdgcn_rcpf(x); }
__device__ __forceinline__ unsigned f2bf(float x) {   // fp32 -> bf16 bits (RNE)
  unsigned u = __float_as_uint(x);
  return (u + 0x7fffu + ((u >> 16) & 1u)) >> 16;
}
__device__ __forceinline__ float bf_lo(unsigned d) { return __uint_as_float(d << 16); }
__device__ __forceinline__ float bf_hi(unsigned d) { return __uint_as_float(d & 0xffff0000u); }

// ---------------- kernel 1: projections -> v (fp32), u & Xy (bf16) --------
// 256 blocks x 512 threads, 4 rows/block (round-3 optimum: full 256-CU
// coverage for fetch parallelism; 2-lane weight-address sharing halves L2
// weight traffic vs 1-lane; 128-block/4-lane variant REGRESSED +3.8us —
// latency-bound regime needs all CUs issuing loads).
__global__ __launch_bounds__(512) void proj_kernel(
    const float* __restrict__ X, const float* __restrict__ by,
    const float* __restrict__ Wo, const float* __restrict__ W1,
    const float* __restrict__ Wy, float* __restrict__ ws) {
  __shared__ float xs[4*C_];
  int row0 = blockIdx.x * 4;            // global row base; 4 | N so no batch straddle
  int t = threadIdx.x;
  xs[t] = X[(size_t)row0*C_ + t];       // 512 threads stage 4 rows
  __syncthreads();

  int rp = t & 1;                       // row-pair: rows rp*2, rp*2+1 (block-local)
  int cu = t >> 1;                      // 0..255 column unit
  const float* wrow;
  int col;
  if (cu < 64)       { col = cu;        wrow = Wo + (size_t)col*C_; }
  else if (cu < 128) { col = cu - 64;   wrow = W1 + (size_t)col*C_; }
  else               { col = cu - 128;  wrow = Wy + (size_t)col*C_; }

  const float* x0 = xs + (rp*2)*C_;
  const float* x1 = xs + (rp*2 + 1)*C_;
  const float4* w4 = (const float4*)wrow;
  float acc0 = 0.f, acc1 = 0.f;
  #pragma unroll 8
  for (int c4 = 0; c4 < C_/4; ++c4) {
    float4 w = w4[c4];
    int c = c4*4;
    acc0 = fmaf(x0[c+0], w.x, acc0);  acc1 = fmaf(x1[c+0], w.x, acc1);
    acc0 = fmaf(x0[c+1], w.y, acc0);  acc1 = fmaf(x1[c+1], w.y, acc1);
    acc0 = fmaf(x0[c+2], w.z, acc0);  acc1 = fmaf(x1[c+2], w.z, acc1);
    acc0 = fmaf(x0[c+3], w.w, acc0);  acc1 = fmaf(x1[c+3], w.w, acc1);
  }

  int grow = row0 + rp*2;               // global row of acc0 (even)
  int b = grow >> 9, n0 = grow & (N_-1);

  if (cu < 64) {                        // v = exp(2 h_o), fp32
    float* o = ws + OFF_V + (size_t)grow*A_ + col;
    o[0] = fexp2(SC2L * acc0);
    o[A_] = fexp2(SC2L * acc1);
  } else if (cu < 128) {                // u = exp(2 h_1), bf16, two layouts
    int a = col;
    unsigned u0 = f2bf(fexp2(SC2L * acc0));
    unsigned u1 = f2bf(fexp2(SC2L * acc1));
    unsigned short* ut = (unsigned short*)(ws + OFF_UT8);
    size_t bA = ((size_t)(b*8 + (a >> 3))*N_ + n0)*8 + (a & 7);
    ut[bA] = (unsigned short)u0;
    ut[bA + 8] = (unsigned short)u1;
    unsigned short* us = (unsigned short*)(ws + OFF_US8);
    size_t bC = ((size_t)(b*64 + (n0 >> 3))*A_ + a)*8 + (n0 & 7);
    us[bC] = (unsigned short)u0;
    us[bC + 1] = (unsigned short)u1;
  } else {                              // Xy bf16 pairs [b][k][h]
    int h = col;
    float bb = by[h];
    unsigned xv0 = f2bf(acc0 + bb);
    unsigned xv1 = f2bf(acc1 + bb);
    unsigned* xp = (unsigned*)(ws + OFF_XYP);
    xp[(size_t)(b*(N_/2) + (n0 >> 1))*H_ + h] = xv0 | (xv1 << 16);
  }
}

// ---------------- kernel 2: attention, TI=4, 1024 threads ----------------
// 256 blocks x 1024 threads = 1 block/CU (16 waves/CU). Pipe-balanced:
// VALU ~2080 cy/wave vs trans ~2048 cy/wave.
__global__ __launch_bounds__(1024) void attn_kernel(
    const float* __restrict__ Wphi, const float* __restrict__ be,
    const float* __restrict__ We,
    const float* __restrict__ ws, float* __restrict__ out) {
  __shared__ __align__(16) float pkv[4][A_]; // v rows (1 KB)
  __shared__ __align__(16) float pkw[A_];    // wphi
  __shared__ float sc[4][N_];                // p_j per row (8 KB)
  __shared__ float reds[4][8];               // per-wave denom partials
  __shared__ float ebw[4][16][A_];           // ebar partials (16 KB)
  __shared__ float ebar[4][A_];
  __shared__ __align__(16) float p1s[4][32][H_];  // part1 partials (64 KB)
  __shared__ float wes[A_*WES_STRIDE];       // We^T [a][h] padded (32.5 KB)

  int t = threadIdx.x;
  int w = t >> 6, lane = t & 63;
  int blk = blockIdx.x;                      // 0..255
  int b = blk >> 7;
  int i0 = (blk & 127) * 4;
  int g0 = b*N_ + i0;

  const uint4* ut8 = (const uint4*)((const unsigned short*)(ws + OFF_UT8))
                     + (size_t)b*8*N_;
  const uint4* us8 = (const uint4*)((const unsigned short*)(ws + OFF_US8))
                     + (size_t)b*64*A_;
  const uint4* xy4 = (const uint4*)((const unsigned*)(ws + OFF_XYP))
                     + (size_t)b*(N_/2)*(H_/4);

  if (t < 4*A_) {
    int r = t >> 6, a = t & 63;
    pkv[r][a] = ws[OFF_V + (size_t)(g0 + r)*A_ + a];
  } else if (t < 5*A_) {
    pkw[t - 4*A_] = Wphi[t - 4*A_];
  }
  // stage We^T: coalesced global read, 2-way-aliased (free) LDS write
  #pragma unroll
  for (int e = t; e < H_*A_; e += 1024) {
    int h = e >> 6, a = e & 63;
    wes[a*WES_STRIDE + h] = We[e];
  }
  __syncthreads();

  // ---- Pass A: thread = (r2 = t>>9, j = t&511); covers rows r2 and r2+2.
  {
    int r2 = t >> 9, j = t & 511;
    const float4* pvA = (const float4*)pkv[r2];
    const float4* pvB = (const float4*)pkv[r2 + 2];
    const float4* pw4 = (const float4*)pkw;
    float sA = 0.f, sB = 0.f;
    #pragma unroll
    for (int g = 0; g < 8; ++g) {
      uint4 d = ut8[(size_t)g*N_ + j];
      float4 a0 = pvA[2*g], a1 = pvA[2*g + 1];
      float4 b0 = pvB[2*g], b1 = pvB[2*g + 1];
      float4 w0 = pw4[2*g], w1 = pw4[2*g + 1];
      float u0 = bf_lo(d.x), u1 = bf_hi(d.x), u2 = bf_lo(d.y), u3 = bf_hi(d.y);
      float u4 = bf_lo(d.z), u5 = bf_hi(d.z), u6 = bf_lo(d.w), u7 = bf_hi(d.w);
      sA = fmaf(w0.x, frcp(fmaf(a0.x, u0, 1.f)), sA);
      sB = fmaf(w0.x, frcp(fmaf(b0.x, u0, 1.f)), sB);
      sA = fmaf(w0.y, frcp(fmaf(a0.y, u1, 1.f)), sA);
      sB = fmaf(w0.y, frcp(fmaf(b0.y, u1, 1.f)), sB);
      sA = fmaf(w0.z, frcp(fmaf(a0.z, u2, 1.f)), sA);
      sB = fmaf(w0.z, frcp(fmaf(b0.z, u2, 1.f)), sB);
      sA = fmaf(w0.w, frcp(fmaf(a0.w, u3, 1.f)), sA);
      sB = fmaf(w0.w, frcp(fmaf(b0.w, u3, 1.f)), sB);
      sA = fmaf(w1.x, frcp(fmaf(a1.x, u4, 1.f)), sA);
      sB = fmaf(w1.x, frcp(fmaf(b1.x, u4, 1.f)), sB);
      sA = fmaf(w1.y, frcp(fmaf(a1.y, u5, 1.f)), sA);
      sB = fmaf(w1.y, frcp(fmaf(b1.y, u5, 1.f)), sB);
      sA = fmaf(w1.z, frcp(fmaf(a1.z, u6, 1.f)), sA);
      sB = fmaf(w1.z, frcp(fmaf(b1.z, u6, 1.f)), sB);
      sA = fmaf(w1.w, frcp(fmaf(a1.w, u7, 1.f)), sA);
      sB = fmaf(w1.w, frcp(fmaf(b1.w, u7, 1.f)), sB);
    }
    float pA = fexp2(NEG2LE * sA);           // shift-free softmax numerators
    float pB = fexp2(NEG2LE * sB);
    sc[r2][j] = pA;
    sc[r2 + 2][j] = pB;
    float qA = pA, qB = pB;
    #pragma unroll
    for (int m = 1; m < 64; m <<= 1) {
      qA += __shfl_xor(qA, m);
      qB += __shfl_xor(qB, m);
    }
    if (lane == 0) {                         // w>>3 == r2
      reds[r2][w & 7] = qA;
      reds[r2 + 2][w & 7] = qB;
    }
  }
  __syncthreads();

  // ---- Pass C: lane = a; wave w covers octets o = oo*16 + w, ALL 4 rows
  {
    float v0 = pkv[0][lane], v1 = pkv[1][lane];
    float v2 = pkv[2][lane], v3 = pkv[3][lane];
    const float4* s40 = (const float4*)sc[0];
    const float4* s41 = (const float4*)sc[1];
    const float4* s42 = (const float4*)sc[2];
    const float4* s43 = (const float4*)sc[3];
    float c0 = 0.f, c1 = 0.f, c2 = 0.f, c3 = 0.f;
    #pragma unroll
    for (int oo = 0; oo < 4; ++oo) {
      int o = oo*16 + w;
      uint4 d = us8[(size_t)o*A_ + lane];
      float u0 = bf_lo(d.x), u1 = bf_hi(d.x), u2 = bf_lo(d.y), u3 = bf_hi(d.y);
      float u4 = bf_lo(d.z), u5 = bf_hi(d.z), u6 = bf_lo(d.w), u7 = bf_hi(d.w);
      float4 pA0 = s40[o*2], pB0 = s40[o*2 + 1];
      float4 pA1 = s41[o*2], pB1 = s41[o*2 + 1];
      float4 pA2 = s42[o*2], pB2 = s42[o*2 + 1];
      float4 pA3 = s43[o*2], pB3 = s43[o*2 + 1];
      #define PC_STEP(UU, F) { \
        float r0 = frcp(fmaf(v0, UU, 1.f)); \
        float r1 = frcp(fmaf(v1, UU, 1.f)); \
        float r2v = frcp(fmaf(v2, UU, 1.f)); \
        float r3v = frcp(fmaf(v3, UU, 1.f)); \
        c0 = fmaf(pA0.F, r0, c0); c1 = fmaf(pA1.F, r1, c1); \
        c2 = fmaf(pA2.F, r2v, c2); c3 = fmaf(pA3.F, r3v, c3); }
      #define PC_STEP2(UU, F) { \
        float r0 = frcp(fmaf(v0, UU, 1.f)); \
        float r1 = frcp(fmaf(v1, UU, 1.f)); \
        float r2v = frcp(fmaf(v2, UU, 1.f)); \
        float r3v = frcp(fmaf(v3, UU, 1.f)); \
        c0 = fmaf(pB0.F, r0, c0); c1 = fmaf(pB1.F, r1, c1); \
        c2 = fmaf(pB2.F, r2v, c2); c3 = fmaf(pB3.F, r3v, c3); }
      PC_STEP(u0, x) PC_STEP(u1, y) PC_STEP(u2, z) PC_STEP(u3, w)
      PC_STEP2(u4, x) PC_STEP2(u5, y) PC_STEP2(u6, z) PC_STEP2(u7, w)
      #undef PC_STEP
      #undef PC_STEP2
    }
    ebw[0][w][lane] = c0;
    ebw[1][w][lane] = c1;
    ebw[2][w][lane] = c2;
    ebw[3][w][lane] = c3;
  }

  // ---- part1: thread = (qd = t>>5 in [0,32), h4 = t&31); each Xy-load
  // feeds all 4 P-rows.
  {
    int h4 = t & 31, qd = t >> 5;
    float s00=0.f,s01=0.f,s02=0.f,s03=0.f;
    float s10=0.f,s11=0.f,s12=0.f,s13=0.f;
    float s20=0.f,s21=0.f,s22=0.f,s23=0.f;
    float s30=0.f,s31=0.f,s32=0.f,s33=0.f;
    const float2* p20 = (const float2*)sc[0];
    const float2* p21 = (const float2*)sc[1];
    const float2* p22 = (const float2*)sc[2];
    const float2* p23 = (const float2*)sc[3];
    #pragma unroll
    for (int kc = 0; kc < 8; ++kc) {
      int k = qd*8 + kc;
      uint4 d = xy4[(size_t)k*(H_/4) + h4];
      float2 P0 = p20[k], P1 = p21[k], P2 = p22[k], P3 = p23[k];
      float xa = bf_lo(d.x), xb = bf_hi(d.x);
      float xc = bf_lo(d.y), xd = bf_hi(d.y);
      float xe = bf_lo(d.z), xf = bf_hi(d.z);
      float xg = bf_lo(d.w), xh = bf_hi(d.w);
      s00 = fmaf(P0.x, xa, s00); s00 = fmaf(P0.y, xb, s00);
      s01 = fmaf(P0.x, xc, s01); s01 = fmaf(P0.y, xd, s01);
      s02 = fmaf(P0.x, xe, s02); s02 = fmaf(P0.y, xf, s02);
      s03 = fmaf(P0.x, xg, s03); s03 = fmaf(P0.y, xh, s03);
      s10 = fmaf(P1.x, xa, s10); s10 = fmaf(P1.y, xb, s10);
      s11 = fmaf(P1.x, xc, s11); s11 = fmaf(P1.y, xd, s11);
      s12 = fmaf(P1.x, xe, s12); s12 = fmaf(P1.y, xf, s12);
      s13 = fmaf(P1.x, xg, s13); s13 = fmaf(P1.y, xh, s13);
      s20 = fmaf(P2.x, xa, s20); s20 = fmaf(P2.y, xb, s20);
      s21 = fmaf(P2.x, xc, s21); s21 = fmaf(P2.y, xd, s21);
      s22 = fmaf(P2.x, xe, s22); s22 = fmaf(P2.y, xf, s22);
      s23 = fmaf(P2.x, xg, s23); s23 = fmaf(P2.y, xh, s23);
      s30 = fmaf(P3.x, xa, s30); s30 = fmaf(P3.y, xb, s30);
      s31 = fmaf(P3.x, xc, s31); s31 = fmaf(P3.y, xd, s31);
      s32 = fmaf(P3.x, xe, s32); s32 = fmaf(P3.y, xf, s32);
      s33 = fmaf(P3.x, xg, s33); s33 = fmaf(P3.y, xh, s33);
    }
    *(float4*)&p1s[0][qd][h4*4] = make_float4(s00, s01, s02, s03);
    *(float4*)&p1s[1][qd][h4*4] = make_float4(s10, s11, s12, s13);
    *(float4*)&p1s[2][qd][h4*4] = make_float4(s20, s21, s22, s23);
    *(float4*)&p1s[3][qd][h4*4] = make_float4(s30, s31, s32, s33);
  }
  __syncthreads();

  // ---- reduce ebar: ebar_un[r][a] = l_r - 2*sum_w ebw[r][w][a]
  if (t < 4*A_) {
    int r = t >> 6, a = t & 63;
    float e = 0.f;
    #pragma unroll
    for (int k = 0; k < 16; ++k) e += ebw[r][k][a];
    float l = 0.f;
    #pragma unroll
    for (int k = 0; k < 8; ++k) l += reds[r][k];
    ebar[r][a] = l - 2.0f*e;
  }
  __syncthreads();

  // ---- epilogue: out = (part1_un + We^T·ebar_un)/l + be
  if (t < 4*H_) {
    int r = t >> 7, h = t & 127;
    float l = 0.f;
    #pragma unroll
    for (int k = 0; k < 8; ++k) l += reds[r][k];
    float acc = 0.f;
    #pragma unroll
    for (int k = 0; k < 32; ++k) acc += p1s[r][k][h];
    float e2 = 0.f;
    #pragma unroll 8
    for (int a = 0; a < A_; ++a) e2 = fmaf(ebar[r][a], wes[a*WES_STRIDE + h], e2);
    out[(size_t)(g0 + r)*H_ + h] = (acc + e2) * frcp(l) + be[h];
  }
}

extern "C" void kernel_launch(void* const* d_in, const int* in_sizes, int n_in,
                              void* d_out, int out_size, void* d_ws, size_t ws_size,
                              hipStream_t stream) {
  const float* X    = (const float*)d_in[0];
  const float* Wo   = (const float*)d_in[1];
  const float* W1   = (const float*)d_in[2];
  const float* Wphi = (const float*)d_in[3];
  const float* Wy   = (const float*)d_in[4];
  const float* by   = (const float*)d_in[5];
  const float* We   = (const float*)d_in[6];
  const float* be   = (const float*)d_in[7];
  float* out = (float*)d_out;
  float* ws  = (float*)d_ws;

  hipLaunchKernelGGL(proj_kernel, dim3(B_*N_/4), dim3(512), 0, stream,
                     X, by, Wo, W1, Wy, ws);
  hipLaunchKernelGGL(attn_kernel, dim3(B_*N_/4), dim3(1024), 0, stream,
                     Wphi, be, We, ws, out);
}